// Round 4
// baseline (16826.654 us; speedup 1.0000x reference)
//
#include <hip/hip_runtime.h>

#define LN_EPS 1e-3f

typedef short s8v __attribute__((ext_vector_type(8)));
typedef float f4v __attribute__((ext_vector_type(4)));
typedef unsigned short u16;

__device__ __forceinline__ u16 f2bf(float f) {
  unsigned int x = __float_as_uint(f);
  x += 0x7fffu + ((x >> 16) & 1u);
  return (u16)(x >> 16);
}
__device__ __forceinline__ float bf2f(u16 u) {
  return __uint_as_float(((unsigned int)u) << 16);
}

__device__ __forceinline__ void glds16(const u16* g, void* l) {
  __builtin_amdgcn_global_load_lds(
      (const __attribute__((address_space(1))) void*)g,
      (__attribute__((address_space(3))) void*)l, 16, 0, 0);
}
__device__ __forceinline__ void glds4(const u16* g, void* l) {
  __builtin_amdgcn_global_load_lds(
      (const __attribute__((address_space(1))) void*)g,
      (__attribute__((address_space(3))) void*)l, 4, 0, 0);
}

#define RAW_BAR() do { __builtin_amdgcn_s_barrier(); __builtin_amdgcn_sched_barrier(0); } while (0)

// ---------------- fp32 -> bf16 conversion ----------------
__global__ void k_cvt(const float* __restrict__ src, u16* __restrict__ dst, int n) {
  int i = blockIdx.x * blockDim.x + threadIdx.x;
  int stride = gridDim.x * blockDim.x;
  for (; i < n; i += stride) dst[i] = f2bf(src[i]);
}

// pack GRU weights, h-part-first stage order:
// wt[nt(32)][s(48)][sub(3)][ch(8)][row(64)][8]
// s<32: K-cols = whh[:, s*64...], s>=32: K-cols = wih[:, (s-32)*64...]
// sub0=r rows j, sub1=u rows 2048+j, sub2=c rows 4096+j
__global__ void k_packgru(const float* __restrict__ wih,
                          const float* __restrict__ whh, u16* __restrict__ wt) {
  int u = blockIdx.x * 256 + threadIdx.x;  // 16B units, total 2359296
  int nt = u / 73728;
  int r1 = u % 73728;
  int s = r1 / 1536;
  int r2 = r1 % 1536;
  int sub = r2 / 512;
  int r3 = r2 % 512;
  int ch = r3 / 64;
  int row = r3 % 64;
  int j = sub * 2048 + nt * 64 + row;
  s8v v;
#pragma unroll
  for (int e = 0; e < 8; ++e) {
    float x;
    if (s < 32) {
      x = whh[(size_t)j * 2048 + s * 64 + ch * 8 + e];
    } else {
      x = wih[(size_t)j * 1024 + (s - 32) * 64 + ch * 8 + e];
    }
    v[e] = (short)f2bf(x);
  }
  *(s8v*)(wt + (size_t)u * 8) = v;
}

// generic chunk-linear pack: dst[nt][s][ch(8)][row(BN)][8] from src[N][K] f32
__global__ void k_packB(const float* __restrict__ src, u16* __restrict__ dst,
                        int K, int BN, int total) {
  int u = blockIdx.x * 256 + threadIdx.x;
  if (u >= total) return;
  int ns = K >> 6;
  int perNt = ns * 8 * BN;
  int nt = u / perNt;
  int r1 = u % perNt;
  int s = r1 / (8 * BN);
  int r2 = r1 % (8 * BN);
  int ch = r2 / BN;
  int row = r2 % BN;
  int j = nt * BN + row;
  int k = s * 64 + ch * 8;
  const float* sp = src + (size_t)j * K + k;
  s8v v;
#pragma unroll
  for (int e = 0; e < 8; ++e) v[e] = (short)f2bf(sp[e]);
  *(s8v*)(dst + (size_t)u * 8) = v;
}

// h0 -> hf (f32) and hcat (bf16)
__global__ void k_hinit(const float* __restrict__ h0, float* __restrict__ hf,
                        u16* __restrict__ hcat) {
  int i = blockIdx.x * 256 + threadIdx.x;  // 524288
  float v = h0[i];
  hf[i] = v;
  hcat[i] = f2bf(v);
}

// ---------------- fused za + 3-gate GRU GEMM + gate math + h update --------
// grid 256 (XCD-chunked), 512 thr / 8 waves. BM=32, BN=64, BK=64.
// Stages 0..31: A = h (glds from hcat), B = whh. Stages 32..47: A = za
// (computed in prologue into swizzled LDS), B = wih.
__global__ __launch_bounds__(512) void k_gru(
    const float* __restrict__ zsrc, const float* __restrict__ act,
    const float* __restrict__ zw, const float* __restrict__ zb,
    const float* __restrict__ aw, const float* __restrict__ lnzs,
    const float* __restrict__ lnzb, const u16* __restrict__ hcat_r,
    const u16* __restrict__ wt, const float* __restrict__ bih,
    const float* __restrict__ bhh, const float* __restrict__ hf_r,
    float* __restrict__ hf_w, u16* __restrict__ hcat_w,
    float* __restrict__ feat, int t) {
  const int hw = blockIdx.x;
  const int logical = (hw & 7) * 32 + (hw >> 3);  // chunked XCD swizzle
  const int mg = logical & 7;
  const int nt = logical >> 3;
  const int m0 = mg * 32;
  const int tid = threadIdx.x;
  const int lane = tid & 63;
  const int w = tid >> 6;  // 0..7
  const int lr = lane & 15, lk = lane >> 4;
  const int mh = w & 1, cs = w >> 1;

  __shared__ __align__(16) char bufs[2][28672];   // A 4KB + B 24KB each
  __shared__ __align__(16) char zals[16][4096];   // za A-tiles, swizzled

  const u16* wtNt = wt + (size_t)nt * 48 * 12288;

  // A-glds (H stages): 2 quarter-chunks (glds4) per wave, uniform counts
  const int q0 = w * 2, q1 = w * 2 + 1;
  const int row0 = q0 * 2 + (lane >> 5), row1 = q1 * 2 + (lane >> 5);
  const int slot = (lane & 31) >> 2, b4 = lane & 3;
  const u16* aS0 = hcat_r + (size_t)(m0 + row0) * 2048 +
                   ((slot ^ (row0 & 7)) << 3) + (b4 << 1);
  const u16* aS1 = hcat_r + (size_t)(m0 + row1) * 2048 +
                   ((slot ^ (row1 & 7)) << 3) + (b4 << 1);

  f4v accr = (f4v)(0.f), accu = (f4v)(0.f), acci = (f4v)(0.f), acch = (f4v)(0.f);

#define K1_STAGEH(BB, S) { \
    char* base = &bufs[BB][0]; \
    glds4(aS0 + (S) * 64, base + q0 * 256); \
    glds4(aS1 + (S) * 64, base + q1 * 256); \
    const u16* bsrc = wtNt + (size_t)(S) * 12288; \
    _Pragma("unroll") for (int j = 0; j < 3; ++j) { \
      int c = w + j * 8; \
      glds16(bsrc + c * 512 + lane * 8, base + 4096 + c * 1024); \
    } }

#define K1_STAGEZ(BB, S) { \
    char* base = &bufs[BB][0]; \
    const u16* bsrc = wtNt + (size_t)(S) * 12288; \
    _Pragma("unroll") for (int j = 0; j < 3; ++j) { \
      int c = w + j * 8; \
      glds16(bsrc + c * 512 + lane * 8, base + 4096 + c * 1024); \
    } }

#define K1_COMP(BB, ABASE, ACCX) { \
    char* base = &bufs[BB][0]; \
    _Pragma("unroll") for (int kk = 0; kk < 2; ++kk) { \
      int ch = kk * 4 + lk; \
      int r = mh * 16 + lr; \
      s8v a = *(const s8v*)((ABASE) + r * 128 + ((ch ^ (r & 7)) << 4)); \
      int boff = 4096 + ch * 1024 + ((cs * 16 + lr) << 4); \
      s8v br = *(const s8v*)(base + boff); \
      s8v bu = *(const s8v*)(base + boff + 8192); \
      s8v bx = *(const s8v*)(base + boff + 16384); \
      accr = __builtin_amdgcn_mfma_f32_16x16x32_bf16(a, br, accr, 0, 0, 0); \
      accu = __builtin_amdgcn_mfma_f32_16x16x32_bf16(a, bu, accu, 0, 0, 0); \
      ACCX = __builtin_amdgcn_mfma_f32_16x16x32_bf16(a, bx, ACCX, 0, 0, 0); \
    } }

  // prologue: prefetch stage 0, then compute za into zals (hidden under loads)
  K1_STAGEH(0, 0)
  {
    const int zrow = tid >> 4, g = tid & 15;
    const int grow = m0 + zrow;
    char* zbase = &zals[0][0] + zrow * 128;
    float4 zv[16];
    const float4* zp = (const float4*)(zsrc + grow * 64);
#pragma unroll
    for (int k = 0; k < 16; ++k) zv[k] = zp[k];
    float sacc = 0.f, qacc = 0.f;
#pragma unroll 1
    for (int cc = 0; cc < 32; ++cc) {
      int c = g * 32 + cc;
      const float4* wp = (const float4*)(zw + c * 64);
      float a = zb[c];
#pragma unroll
      for (int k = 0; k < 16; ++k) {
        float4 wv = wp[k];
        a += zv[k].x * wv.x + zv[k].y * wv.y + zv[k].z * wv.z + zv[k].w * wv.w;
      }
      sacc += a;
      qacc += a * a;
      *(u16*)(zbase + (c >> 6) * 4096 + ((((c >> 3) & 7) ^ (zrow & 7)) << 4) +
              ((c & 7) << 1)) = f2bf(a);
    }
    float av[10];
#pragma unroll
    for (int k = 0; k < 10; ++k) av[k] = act[grow * 10 + k];
#pragma unroll 1
    for (int cc = 0; cc < 32; ++cc) {
      int c2 = g * 32 + cc;
      const float* ap = aw + c2 * 10;
      float a = 0.f;
#pragma unroll
      for (int k = 0; k < 10; ++k) a += av[k] * ap[k];
      sacc += a;
      qacc += a * a;
      int c = 512 + c2;
      *(u16*)(zbase + (c >> 6) * 4096 + ((((c >> 3) & 7) ^ (zrow & 7)) << 4) +
              ((c & 7) << 1)) = f2bf(a);
    }
#pragma unroll
    for (int o = 1; o < 16; o <<= 1) {
      sacc += __shfl_xor(sacc, o);
      qacc += __shfl_xor(qacc, o);
    }
    float mu = sacc * (1.f / 1024.f);
    float rs = rsqrtf(qacc * (1.f / 1024.f) - mu * mu + LN_EPS);
#pragma unroll 1
    for (int cc = 0; cc < 64; ++cc) {
      int c = (cc < 32) ? (g * 32 + cc) : (512 + g * 32 + cc - 32);
      u16* p = (u16*)(zbase + (c >> 6) * 4096 +
                      ((((c >> 3) & 7) ^ (zrow & 7)) << 4) + ((c & 7) << 1));
      float x = bf2f(*p);
      float y = (x - mu) * rs * lnzs[c] + lnzb[c];
      y = y > 0.f ? y : expm1f(y);
      *p = f2bf(y);
    }
  }
  asm volatile("s_waitcnt lgkmcnt(0)" ::: "memory");
  RAW_BAR();

  // main loop: counted vmcnt, loads span barriers (never drain to 0 in-loop)
  for (int s = 0; s < 31; ++s) {
    K1_STAGEH((s + 1) & 1, s + 1)
    asm volatile("s_waitcnt vmcnt(5)" ::: "memory");
    RAW_BAR();
    K1_COMP(s & 1, &bufs[s & 1][0], acch)
    RAW_BAR();
  }
  {  // s = 31
    K1_STAGEZ(0, 32)
    asm volatile("s_waitcnt vmcnt(3)" ::: "memory");
    RAW_BAR();
    K1_COMP(1, &bufs[1][0], acch)
    RAW_BAR();
  }
  for (int s = 32; s < 47; ++s) {
    K1_STAGEZ((s + 1) & 1, s + 1)
    asm volatile("s_waitcnt vmcnt(3)" ::: "memory");
    RAW_BAR();
    K1_COMP(s & 1, &zals[s - 32][0], acci)
    RAW_BAR();
  }
  {  // s = 47
    asm volatile("s_waitcnt vmcnt(0)" ::: "memory");
    RAW_BAR();
    K1_COMP(1, &zals[15][0], acci)
  }

  // epilogue: gate math. C/D: col=lane&15, row=(lane>>4)*4+reg
  const int col = nt * 64 + cs * 16 + lr;
  const float b_ri = bih[col], b_rh = bhh[col];
  const float b_ui = bih[2048 + col], b_uh = bhh[2048 + col];
  const float b_ci = bih[4096 + col], b_ch = bhh[4096 + col];
#pragma unroll
  for (int r = 0; r < 4; ++r) {
    int grow = m0 + mh * 16 + lk * 4 + r;
    float vr = accr[r] + b_ri + b_rh;
    float vu = accu[r] + b_ui + b_uh;
    float ic = acci[r] + b_ci;
    float hc = acch[r] + b_ch;
    float rg = 1.f / (1.f + expf(-vr));
    float ug = 1.f / (1.f + expf(-vu));
    float c = tanhf(ic + rg * hc);
    float hold = hf_r[(size_t)grow * 2048 + col];
    float h1 = (1.f - ug) * c + ug * hold;
    hf_w[(size_t)grow * 2048 + col] = h1;
    hcat_w[(size_t)grow * 2048 + col] = f2bf(h1);
    feat[(size_t)(t * 256 + grow) * 2112 + col] = h1;
  }
#undef K1_STAGEH
#undef K1_STAGEZ
#undef K1_COMP
}

// ---------------- posterior hidden GEMM: x = h1@posthW^T + b + e_part ------
// grid 128 (XCD swizzled), 256 thr, BM=32, BN=64, 32 stages, counted vmcnt.
__global__ __launch_bounds__(256) void k_post(
    const u16* __restrict__ hcat, const u16* __restrict__ wp,
    const float* __restrict__ bias, const u16* __restrict__ epart_t,
    float* __restrict__ xbuf) {
  const int hw = blockIdx.x;
  const int logical = (hw & 7) * 16 + (hw >> 3);
  const int mg = logical & 7, nt = logical >> 3;
  const int m0 = mg * 32;
  const int tid = threadIdx.x;
  const int lane = tid & 63;
  const int w = tid >> 6;
  const int lr = lane & 15, lk = lane >> 4;

  __shared__ __align__(16) char smem[2][12288];  // A 4KB + B 8KB

  const int arow = 8 * w + (lane >> 3);
  const int acol8 = ((lane & 7) ^ (arow & 7)) * 8;
  const u16* aSrc = hcat + (size_t)(m0 + arow) * 2048 + acol8;
  const u16* wpNt = wp + (size_t)nt * 32 * 4096;

  f4v acc[2];
  acc[0] = (f4v)(0.f);
  acc[1] = (f4v)(0.f);

#define K2_STAGE(BB, S) { \
    char* base = &smem[BB][0]; \
    glds16(aSrc + (S) * 64, base + w * 1024); \
    const u16* bsrc = wpNt + (size_t)(S) * 4096; \
    _Pragma("unroll") for (int i = 0; i < 2; ++i) { \
      int cf = w + i * 4; \
      glds16(bsrc + (cf * 64 + lane) * 8, base + 4096 + cf * 1024); \
    } }

#define K2_COMP(BB) { \
    char* base = &smem[BB][0]; \
    _Pragma("unroll") for (int kk = 0; kk < 2; ++kk) { \
      int ch = kk * 4 + lk; \
      int r0 = lr, r1 = 16 + lr; \
      s8v a0 = *(const s8v*)(base + r0 * 128 + ((ch ^ (r0 & 7)) * 16)); \
      s8v a1 = *(const s8v*)(base + r1 * 128 + ((ch ^ (r1 & 7)) * 16)); \
      s8v b = *(const s8v*)(base + 4096 + ch * 1024 + (w * 16 + lr) * 16); \
      acc[0] = __builtin_amdgcn_mfma_f32_16x16x32_bf16(a0, b, acc[0], 0, 0, 0); \
      acc[1] = __builtin_amdgcn_mfma_f32_16x16x32_bf16(a1, b, acc[1], 0, 0, 0); \
    } }

  K2_STAGE(0, 0)
  for (int s = 0; s < 31; ++s) {
    K2_STAGE((s + 1) & 1, s + 1)
    asm volatile("s_waitcnt vmcnt(3)" ::: "memory");
    RAW_BAR();
    K2_COMP(s & 1)
    RAW_BAR();
  }
  {
    asm volatile("s_waitcnt vmcnt(0)" ::: "memory");
    RAW_BAR();
    K2_COMP(1)
  }
  const int col = nt * 64 + w * 16 + lr;
#pragma unroll
  for (int m = 0; m < 2; ++m) {
#pragma unroll
    for (int r = 0; r < 4; ++r) {
      int grow = m0 + m * 16 + lk * 4 + r;
      float v = acc[m][r] + bias[col] + bf2f(epart_t[(size_t)grow * 1024 + col]);
      xbuf[(size_t)grow * 1024 + col] = v;
    }
  }
#undef K2_STAGE
#undef K2_COMP
}

// ------------- posterior head: LN+ELU (fused A-stage) + GEMM + z-sample ----
__global__ __launch_bounds__(512) void k_postz(
    const float* __restrict__ xb, const u16* __restrict__ pw,
    const float* __restrict__ lns, const float* __restrict__ lnb,
    const float* __restrict__ pb, float* __restrict__ posts_t,
    const float* __restrict__ noise_t, float* __restrict__ zout,
    float* __restrict__ feat, int t) {
  const int m0 = blockIdx.x * 32;
  const int tid = threadIdx.x;
  const int lane = tid & 63;
  const int w = tid >> 6;  // 0..7
  const int lr = lane & 15, lk = lane >> 4;
  __shared__ __align__(16) u16 As[2][32][64];
  __shared__ __align__(16) u16 Bs[2][8][128][8];
  __shared__ float lmu[32], lrs[32];
  __shared__ float ps[32][132];
  {
    int row = tid >> 4, sg = tid & 15;
    const float4* xp = (const float4*)(xb + (size_t)(m0 + row) * 1024 + sg * 64);
    float s = 0.f, q = 0.f;
#pragma unroll
    for (int i = 0; i < 16; ++i) {
      float4 v = xp[i];
      s += v.x + v.y + v.z + v.w;
      q += v.x * v.x + v.y * v.y + v.z * v.z + v.w * v.w;
    }
#pragma unroll
    for (int o = 1; o < 16; o <<= 1) {
      s += __shfl_xor(s, o);
      q += __shfl_xor(q, o);
    }
    if (sg == 0) {
      float mu = s * (1.f / 1024.f);
      lmu[row] = mu;
      lrs[row] = rsqrtf(q * (1.f / 1024.f) - mu * mu + LN_EPS);
    }
  }
  __syncthreads();

#define K3_STAGEA(BB, S) if (tid < 256) { \
    int row = tid >> 3, k8 = tid & 7; \
    const float* xp = xb + (size_t)(m0 + row) * 1024 + (S) * 64 + k8 * 8; \
    float mu = lmu[row], rs = lrs[row]; \
    s8v v; \
    _Pragma("unroll") for (int e = 0; e < 8; ++e) { \
      int c = (S) * 64 + k8 * 8 + e; \
      float y = (xp[e] - mu) * rs * lns[c] + lnb[c]; \
      y = y > 0.f ? y : expm1f(y); \
      v[e] = (short)f2bf(y); \
    } \
    *(s8v*)((char*)&As[BB][0][0] + row * 128 + ((k8 ^ (row & 7)) * 16)) = v; }

#define K3_STAGEB(BB, S) { \
    const u16* bsrc = pw + (size_t)(S) * 8192; \
    glds16(bsrc + (((w >> 1) * 128 + (w & 1) * 64 + lane) * 8), \
           (char*)&Bs[BB][0][0][0] + w * 1024); \
    glds16(bsrc + ((((w >> 1) + 4) * 128 + (w & 1) * 64 + lane) * 8), \
           (char*)&Bs[BB][0][0][0] + w * 1024 + 8192); }

  f4v acc[2];
  acc[0] = (f4v)(0.f);
  acc[1] = (f4v)(0.f);
  K3_STAGEA(0, 0)
  K3_STAGEB(0, 0)
  int buf = 0;
  for (int s = 0; s < 16; ++s) {
    if (s + 1 < 16) {
      K3_STAGEA(buf ^ 1, s + 1)
      K3_STAGEB(buf ^ 1, s + 1)
      asm volatile("s_waitcnt vmcnt(2) lgkmcnt(0)" ::: "memory");
    } else {
      asm volatile("s_waitcnt vmcnt(0) lgkmcnt(0)" ::: "memory");
    }
    RAW_BAR();
#pragma unroll
    for (int kk = 0; kk < 2; ++kk) {
      int ch = kk * 4 + lk;
      int r0 = lr, r1 = 16 + lr;
      s8v a0 = *(const s8v*)((char*)&As[buf][0][0] + r0 * 128 + ((ch ^ (r0 & 7)) * 16));
      s8v a1 = *(const s8v*)((char*)&As[buf][0][0] + r1 * 128 + ((ch ^ (r1 & 7)) * 16));
      s8v b = *(const s8v*)((char*)&Bs[buf][0][0][0] + ch * 2048 + (w * 16 + lr) * 16);
      acc[0] = __builtin_amdgcn_mfma_f32_16x16x32_bf16(a0, b, acc[0], 0, 0, 0);
      acc[1] = __builtin_amdgcn_mfma_f32_16x16x32_bf16(a1, b, acc[1], 0, 0, 0);
    }
    __builtin_amdgcn_s_barrier();
    buf ^= 1;
  }
#pragma unroll
  for (int m = 0; m < 2; ++m) {
#pragma unroll
    for (int r = 0; r < 4; ++r) {
      int row = m * 16 + lk * 4 + r;
      int col = w * 16 + lr;
      float v = acc[m][r] + pb[col];
      posts_t[(size_t)(m0 + row) * 128 + col] = v;
      ps[row][col] = v;
    }
  }
  __syncthreads();
#pragma unroll
  for (int q = 0; q < 4; ++q) {
    int e = q * 512 + tid;
    int row = e >> 6, j = e & 63;
    float mean = ps[row][j], sraw = ps[row][64 + j];
    float sd = 2.f / (1.f + expf(-sraw)) + 0.1f;
    float z = mean + sd * noise_t[(m0 + row) * 64 + j];
    zout[(m0 + row) * 64 + j] = z;
    feat[(size_t)(t * 256 + m0 + row) * 2112 + 2048 + j] = z;
  }
#undef K3_STAGEA
#undef K3_STAGEB
}

// ---------------- batched 8-wave GEMM (embed / prior phases) ----------------
template <bool AF32, bool OUTBF16>
__global__ __launch_bounds__(512) void k_gemm8(
    const void* __restrict__ Av, int lda, const u16* __restrict__ Bw, int ldb,
    int nstage, float* __restrict__ Cf, u16* __restrict__ Cb, int ldc,
    const float* __restrict__ bias) {
  const int bx = blockIdx.x, by = blockIdx.y;
  const int tid = threadIdx.x;
  const int m0 = bx * 64;
  const int n0 = by * 128;
  __shared__ __align__(16) u16 As[64][72];
  __shared__ __align__(16) u16 Bs[128][72];
  const int lane = tid & 63;
  const int w = tid >> 6;
  const int wr = w >> 2;
  const int wc = w & 3;
  const int lr = lane & 15;
  const int lk = lane >> 4;

  f4v acc[2][2];
#pragma unroll
  for (int m = 0; m < 2; ++m)
#pragma unroll
    for (int n = 0; n < 2; ++n) acc[m][n] = (f4v)(0.0f);

  for (int s = 0; s < nstage; ++s) {
    const int k0 = s << 6;
    {
      int row = tid >> 3, k8 = (tid & 7) << 3;
      if (AF32) {
        const float* ap = (const float*)Av + (size_t)(m0 + row) * lda + k0 + k8;
        float4 f0 = *(const float4*)ap;
        float4 f1 = *(const float4*)(ap + 4);
        s8v v;
        v[0] = (short)f2bf(f0.x); v[1] = (short)f2bf(f0.y);
        v[2] = (short)f2bf(f0.z); v[3] = (short)f2bf(f0.w);
        v[4] = (short)f2bf(f1.x); v[5] = (short)f2bf(f1.y);
        v[6] = (short)f2bf(f1.z); v[7] = (short)f2bf(f1.w);
        *(s8v*)&As[row][k8] = v;
      } else {
        *(s8v*)&As[row][k8] =
            *(const s8v*)((const u16*)Av + (size_t)(m0 + row) * lda + k0 + k8);
      }
    }
#pragma unroll
    for (int it = 0; it < 2; ++it) {
      int c = tid + it * 512;
      int row = c >> 3, k8 = (c & 7) << 3;
      *(s8v*)&Bs[row][k8] = *(const s8v*)(Bw + (size_t)(n0 + row) * ldb + k0 + k8);
    }
    __syncthreads();
#pragma unroll
    for (int kk = 0; kk < 2; ++kk) {
      const int koff = kk * 32 + lk * 8;
      s8v a[2], b[2];
      a[0] = *(const s8v*)&As[wr * 32 + lr][koff];
      a[1] = *(const s8v*)&As[wr * 32 + 16 + lr][koff];
      b[0] = *(const s8v*)&Bs[wc * 32 + lr][koff];
      b[1] = *(const s8v*)&Bs[wc * 32 + 16 + lr][koff];
#pragma unroll
      for (int m = 0; m < 2; ++m)
#pragma unroll
        for (int n = 0; n < 2; ++n)
          acc[m][n] =
              __builtin_amdgcn_mfma_f32_16x16x32_bf16(a[m], b[n], acc[m][n], 0, 0, 0);
    }
    __syncthreads();
  }
#pragma unroll
  for (int m = 0; m < 2; ++m) {
#pragma unroll
    for (int n = 0; n < 2; ++n) {
#pragma unroll
      for (int r = 0; r < 4; ++r) {
        int row = m0 + wr * 32 + m * 16 + lk * 4 + r;
        int col = n0 + wc * 32 + n * 16 + lr;
        float v = acc[m][n][r];
        if (bias) v += bias[col];
        if (OUTBF16)
          Cb[(size_t)row * ldc + col] = f2bf(v);
        else
          Cf[(size_t)row * ldc + col] = v;
      }
    }
  }
}

// ---------------- LN + ELU (rows of 1024), bf16 in/out ----------------
__global__ __launch_bounds__(256) void k_lnelu(const u16* __restrict__ xsrc,
                                               const float* __restrict__ s,
                                               const float* __restrict__ bb,
                                               u16* __restrict__ out) {
  int row = blockIdx.x, tid = threadIdx.x;
  __shared__ float red[256];
  float v[4];
#pragma unroll
  for (int i = 0; i < 4; ++i) {
    size_t idx = (size_t)row * 1024 + tid + i * 256;
    v[i] = bf2f(xsrc[idx]);
  }
  float sm = v[0] + v[1] + v[2] + v[3];
  red[tid] = sm;
  __syncthreads();
  for (int o = 128; o > 0; o >>= 1) {
    if (tid < o) red[tid] += red[tid + o];
    __syncthreads();
  }
  float mu = red[0] * (1.0f / 1024.0f);
  __syncthreads();
  float q = 0.f;
#pragma unroll
  for (int i = 0; i < 4; ++i) {
    float d = v[i] - mu;
    q += d * d;
  }
  red[tid] = q;
  __syncthreads();
  for (int o = 128; o > 0; o >>= 1) {
    if (tid < o) red[tid] += red[tid + o];
    __syncthreads();
  }
  float rs = rsqrtf(red[0] * (1.0f / 1024.0f) + LN_EPS);
#pragma unroll
  for (int i = 0; i < 4; ++i) {
    int c = tid + i * 256;
    float y = (v[i] - mu) * rs * s[c] + bb[c];
    y = y > 0.f ? y : expm1f(y);
    out[(size_t)row * 1024 + c] = f2bf(y);
  }
}

extern "C" void kernel_launch(void* const* d_in, const int* in_sizes, int n_in,
                              void* d_out, int out_size, void* d_ws,
                              size_t ws_size, hipStream_t stream) {
  const float* embeds = (const float*)d_in[0];
  const float* actions = (const float*)d_in[1];
  const float* h_t = (const float*)d_in[2];
  const float* z_t = (const float*)d_in[3];
  const float* noise = (const float*)d_in[4];
  const float* z_mlp_w = (const float*)d_in[5];
  const float* z_mlp_b = (const float*)d_in[6];
  const float* a_mlp_w = (const float*)d_in[7];
  const float* ln_za_s = (const float*)d_in[8];
  const float* ln_za_b = (const float*)d_in[9];
  const float* gru_wih = (const float*)d_in[10];
  const float* gru_whh = (const float*)d_in[11];
  const float* gru_bih = (const float*)d_in[12];
  const float* gru_bhh = (const float*)d_in[13];
  const float* post_h_w = (const float*)d_in[14];
  const float* post_h_b = (const float*)d_in[15];
  const float* post_e_w = (const float*)d_in[16];
  const float* post_e_b = (const float*)d_in[17];
  const float* ln_post_s = (const float*)d_in[18];
  const float* ln_post_b = (const float*)d_in[19];
  const float* post_w = (const float*)d_in[20];
  const float* post_b = (const float*)d_in[21];
  const float* prior_h_w = (const float*)d_in[22];
  const float* prior_h_b = (const float*)d_in[23];
  const float* ln_prior_s = (const float*)d_in[24];
  const float* ln_prior_b = (const float*)d_in[25];
  const float* prior_w = (const float*)d_in[26];
  const float* prior_b = (const float*)d_in[27];

  float* out = (float*)d_out;
  float* out_priors = out;           // [64,256,128]
  float* out_posts = out + 2097152;  // [64,256,128]
  float* out_z = out + 4194304;      // [64,256,64]
  float* out_feat = out + 5242880;   // [64,256,2112]

  char* ws = (char*)d_ws;
  size_t off = 0;
  auto alloc = [&](size_t bytes) {
    char* p = ws + off;
    off += (bytes + 255) & ~(size_t)255;
    return p;
  };
  // region W: GRU wt pack during scan; prx_b during prior phase
  char* regW = alloc((size_t)32 * 48 * 12288 * 2);  // 37.75 MB
  u16* wt = (u16*)regW;
  u16* prx_b = (u16*)regW;
  u16* posthP = (u16*)alloc((size_t)1024 * 2048 * 2);
  u16* postwP = (u16*)alloc((size_t)128 * 1024 * 2);
  u16* poste_b = (u16*)alloc((size_t)1024 * 1536 * 2);
  u16* priorh_b = (u16*)alloc((size_t)1024 * 2048 * 2);
  u16* priorw_b = (u16*)alloc((size_t)128 * 1024 * 2);
  u16* hcat0 = (u16*)alloc((size_t)256 * 2048 * 2);
  u16* hcat1 = (u16*)alloc((size_t)256 * 2048 * 2);
  float* hf0 = (float*)alloc((size_t)256 * 2048 * 4);
  float* hf1 = (float*)alloc((size_t)256 * 2048 * 4);
  float* xbuf = (float*)alloc((size_t)256 * 1024 * 4);
  // region U: e_part during scan; p_pr during prior phase
  char* regU = alloc((size_t)16384 * 1024 * 2);  // 33.55 MB
  u16* e_part = (u16*)regU;
  u16* p_pr = (u16*)regU;

  u16* hcat[2] = {hcat0, hcat1};
  float* hf[2] = {hf0, hf1};

  // ---- packing + conversions + h init ----
  k_packgru<<<9216, 256, 0, stream>>>(gru_wih, gru_whh, wt);
  k_packB<<<1024, 256, 0, stream>>>(post_h_w, posthP, 2048, 64, 262144);
  k_packB<<<64, 256, 0, stream>>>(post_w, postwP, 1024, 128, 16384);
  k_cvt<<<512, 256, 0, stream>>>(post_e_w, poste_b, 1024 * 1536);
  k_cvt<<<512, 256, 0, stream>>>(prior_h_w, priorh_b, 1024 * 2048);
  k_cvt<<<64, 256, 0, stream>>>(prior_w, priorw_b, 128 * 1024);
  k_hinit<<<2048, 256, 0, stream>>>(h_t, hf0, hcat0);

  // ---- batched embed projection: e_part = embeds@post_e_w^T + post_e_b ----
  k_gemm8<true, true><<<dim3(256, 8), 512, 0, stream>>>(
      embeds, 1536, poste_b, 1536, 24, nullptr, e_part, 1024, post_e_b);

  // ---- sequential scan (3 launches/step) ----
  for (int t = 0; t < 64; ++t) {
    const int rI = t & 1, wI = rI ^ 1;
    const float* zsrc = (t == 0) ? z_t : (out_z + (size_t)(t - 1) * 16384);
    k_gru<<<256, 512, 0, stream>>>(zsrc, actions + (size_t)t * 2560, z_mlp_w,
                                   z_mlp_b, a_mlp_w, ln_za_s, ln_za_b,
                                   hcat[rI], wt, gru_bih, gru_bhh, hf[rI],
                                   hf[wI], hcat[wI], out_feat, t);
    k_post<<<128, 256, 0, stream>>>(hcat[wI], posthP, post_h_b,
                                    e_part + (size_t)t * 262144, xbuf);
    k_postz<<<8, 512, 0, stream>>>(xbuf, postwP, ln_post_s, ln_post_b, post_b,
                                   out_posts + (size_t)t * 32768,
                                   noise + (size_t)t * 16384,
                                   out_z + (size_t)t * 16384, out_feat, t);
  }

  // ---- batched prior head (wt/e_part dead; reuse regions) ----
  k_gemm8<true, true><<<dim3(256, 8), 512, 0, stream>>>(
      out_feat, 2112, priorh_b, 2048, 32, nullptr, prx_b, 1024, prior_h_b);
  k_lnelu<<<16384, 256, 0, stream>>>(prx_b, ln_prior_s, ln_prior_b, p_pr);
  k_gemm8<false, false><<<dim3(256, 1), 512, 0, stream>>>(
      p_pr, 1024, priorw_b, 1024, 16, out_priors, nullptr, 128, prior_b);
}

// Round 6
// 8619.462 us; speedup vs baseline: 1.9522x; 1.9522x over previous
//
#include <hip/hip_runtime.h>

#define LN_EPS 1e-3f

typedef short s8v __attribute__((ext_vector_type(8)));
typedef float f4v __attribute__((ext_vector_type(4)));
typedef unsigned short u16;

#define MFMA16 __builtin_amdgcn_mfma_f32_16x16x32_bf16

__device__ __forceinline__ u16 f2bf(float f) {
  unsigned int x = __float_as_uint(f);
  x += 0x7fffu + ((x >> 16) & 1u);
  return (u16)(x >> 16);
}
__device__ __forceinline__ float bf2f(u16 u) {
  return __uint_as_float(((unsigned int)u) << 16);
}

__device__ __forceinline__ void glds16(const u16* g, void* l) {
  __builtin_amdgcn_global_load_lds(
      (const __attribute__((address_space(1))) void*)g,
      (__attribute__((address_space(3))) void*)l, 16, 0, 0);
}

#define RAW_BAR() do { __builtin_amdgcn_s_barrier(); __builtin_amdgcn_sched_barrier(0); } while (0)

// ---------------- fp32 -> bf16 conversion ----------------
__global__ void k_cvt(const float* __restrict__ src, u16* __restrict__ dst, int n) {
  int i = blockIdx.x * blockDim.x + threadIdx.x;
  int stride = gridDim.x * blockDim.x;
  for (; i < n; i += stride) dst[i] = f2bf(src[i]);
}

// pack GRU weights: wt[nt(32)][s(48)][sub(3)][ch(8)][row(64)][8]
// K-order: s<16 -> za cols (wih), s>=16 -> h cols (whh).
// sub0 = r-gate, sub1 = u-gate, sub2 = s<16 ? wih_c : whh_c
__global__ void k_packgru(const float* __restrict__ wih,
                          const float* __restrict__ whh, u16* __restrict__ wt) {
  int u = blockIdx.x * 256 + threadIdx.x;  // 16B units, total 2359296
  int nt = u / 73728;
  int r1 = u % 73728;
  int s = r1 / 1536;
  int r2 = r1 % 1536;
  int sub = r2 / 512;
  int r3 = r2 % 512;
  int ch = r3 / 64;
  int row = r3 % 64;
  int j = nt * 64 + row;
  int kbase = s * 64 + ch * 8;
  s8v v;
#pragma unroll
  for (int e = 0; e < 8; ++e) {
    int kk = kbase + e;
    float x;
    if (sub == 0) {
      x = kk < 1024 ? wih[(size_t)j * 1024 + kk] : whh[(size_t)j * 2048 + kk - 1024];
    } else if (sub == 1) {
      int jj = 2048 + j;
      x = kk < 1024 ? wih[(size_t)jj * 1024 + kk] : whh[(size_t)jj * 2048 + kk - 1024];
    } else {
      int jj = 4096 + j;
      x = (s < 16) ? wih[(size_t)jj * 1024 + kk] : whh[(size_t)jj * 2048 + kk - 1024];
    }
    v[e] = (short)f2bf(x);
  }
  *(s8v*)(wt + (size_t)u * 8) = v;
}

// generic chunk-linear pack: dst[nt][s][ch(8)][row(BN)][8] from src[N][K] f32
__global__ void k_packB(const float* __restrict__ src, u16* __restrict__ dst,
                        int K, int BN, int total) {
  int u = blockIdx.x * 256 + threadIdx.x;
  if (u >= total) return;
  int ns = K >> 6;
  int perNt = ns * 8 * BN;
  int nt = u / perNt;
  int r1 = u % perNt;
  int s = r1 / (8 * BN);
  int r2 = r1 % (8 * BN);
  int ch = r2 / BN;
  int row = r2 % BN;
  int j = nt * BN + row;
  int k = s * 64 + ch * 8;
  const float* sp = src + (size_t)j * K + k;
  s8v v;
#pragma unroll
  for (int e = 0; e < 8; ++e) v[e] = (short)f2bf(sp[e]);
  *(s8v*)(dst + (size_t)u * 8) = v;
}

// awT[k*512+c] = aw[c*10+k]
__global__ void k_trA(const float* __restrict__ aw, float* __restrict__ awT) {
  int i = blockIdx.x * 256 + threadIdx.x;
  if (i >= 5120) return;
  int k = i >> 9, c = i & 511;
  awT[i] = aw[c * 10 + k];
}

// h0 -> hf (f32) and hcat (bf16)
__global__ void k_hinit(const float* __restrict__ h0, float* __restrict__ hf,
                        u16* __restrict__ hcat) {
  int i = blockIdx.x * 256 + threadIdx.x;  // 524288
  float v = h0[i];
  hf[i] = v;
  hcat[i] = f2bf(v);
}

// ---------------- t=0 za: elu(LN(concat(z@zw^T+zb, a@aw^T))) ----------------
__global__ __launch_bounds__(256) void k_za0(
    const float* __restrict__ zsrc, const float* __restrict__ act,
    const float* __restrict__ zw, const float* __restrict__ zb,
    const float* __restrict__ aw, const float* __restrict__ lns,
    const float* __restrict__ lnb, u16* __restrict__ za) {
  const int b = blockIdx.x, tid = threadIdx.x;
  __shared__ float zsh[64];
  __shared__ float ash[12];
  __shared__ float wred[8];
  if (tid < 64) zsh[tid] = zsrc[b * 64 + tid];
  if (tid < 10) ash[tid] = act[b * 10 + tid];
  __syncthreads();
  float x[4];
#pragma unroll
  for (int i = 0; i < 2; ++i) {
    int c = tid + i * 256;
    const float4* wp = (const float4*)(zw + c * 64);
    float a = zb[c];
#pragma unroll
    for (int k = 0; k < 16; ++k) {
      float4 v = wp[k];
      a += zsh[k * 4] * v.x + zsh[k * 4 + 1] * v.y + zsh[k * 4 + 2] * v.z +
           zsh[k * 4 + 3] * v.w;
    }
    x[i] = a;
  }
#pragma unroll
  for (int i = 2; i < 4; ++i) {
    int c2 = tid + (i - 2) * 256;
    const float* wp = aw + c2 * 10;
    float a = 0.f;
#pragma unroll
    for (int k = 0; k < 10; ++k) a += ash[k] * wp[k];
    x[i] = a;
  }
  float s = x[0] + x[1] + x[2] + x[3];
#pragma unroll
  for (int o = 1; o < 64; o <<= 1) s += __shfl_xor(s, o);
  if ((tid & 63) == 0) wred[tid >> 6] = s;
  __syncthreads();
  float mu = (wred[0] + wred[1] + wred[2] + wred[3]) * (1.f / 1024.f);
  float q = 0.f;
#pragma unroll
  for (int i = 0; i < 4; ++i) {
    float d = x[i] - mu;
    q += d * d;
  }
#pragma unroll
  for (int o = 1; o < 64; o <<= 1) q += __shfl_xor(q, o);
  if ((tid & 63) == 0) wred[4 + (tid >> 6)] = q;
  __syncthreads();
  float rs = rsqrtf((wred[4] + wred[5] + wred[6] + wred[7]) * (1.f / 1024.f) + LN_EPS);
  int cols[4] = {tid, tid + 256, 512 + tid, 768 + tid};
#pragma unroll
  for (int i = 0; i < 4; ++i) {
    int c = cols[i];
    float y = (x[i] - mu) * rs * lns[c] + lnb[c];
    y = y > 0.f ? y : expm1f(y);
    za[(size_t)b * 1024 + c] = f2bf(y);
  }
}

// ---------------- fused 3-gate GRU GEMM + gate math + h update -------------
// grid 128 (XCD-chunked), 512 thr. BM=64, BN=64, BK=64, 48 stages,
// depth-3 glds prefetch with counted vmcnt.
__global__ __launch_bounds__(512) void k_gru(
    const u16* __restrict__ za, const u16* __restrict__ hcat_r,
    const u16* __restrict__ wt, const float* __restrict__ bih,
    const float* __restrict__ bhh, const float* __restrict__ hf_r,
    float* __restrict__ hf_w, u16* __restrict__ hcat_w,
    float* __restrict__ feat, int t) {
  const int hw = blockIdx.x;
  const int logical = (hw & 7) * 16 + (hw >> 3);
  const int mg = logical & 3;
  const int nt = logical >> 2;
  const int m0 = mg * 64;
  const int tid = threadIdx.x;
  const int lane = tid & 63;
  const int w = tid >> 6;  // 0..7
  const int lr = lane & 15, lk = lane >> 4;
  const int mh = w & 1, cq = w >> 1;

  __shared__ __align__(16) char bufs[3][32768];  // A 8KB + B 24KB each

  const int arow = w * 8 + (lane >> 3);
  const int acol8 = ((lane & 7) ^ (arow & 7)) * 8;  // pre-swizzled source
  const u16* aZ = za + (size_t)(m0 + arow) * 1024 + acol8;
  const u16* aH = hcat_r + (size_t)(m0 + arow) * 2048 + acol8;
  const u16* wtNt = wt + (size_t)nt * 48 * 12288;

  f4v accr0 = (f4v)(0.f), accr1 = (f4v)(0.f);
  f4v accu0 = (f4v)(0.f), accu1 = (f4v)(0.f);
  f4v acci0 = (f4v)(0.f), acci1 = (f4v)(0.f);
  f4v acch0 = (f4v)(0.f), acch1 = (f4v)(0.f);

#define G_STAGE(S) { \
    char* base = &bufs[(S) % 3][0]; \
    const u16* ap = ((S) < 16) ? (aZ + (S) * 64) : (aH + ((S) - 16) * 64); \
    glds16(ap, base + w * 1024); \
    const u16* bsrc = wtNt + (size_t)(S) * 12288; \
    _Pragma("unroll") for (int jj = 0; jj < 3; ++jj) { \
      int c = w + jj * 8; \
      glds16(bsrc + c * 512 + lane * 8, base + 8192 + c * 1024); \
    } }

#define G_COMP(S, X0, X1) { \
    char* base = &bufs[(S) % 3][0]; \
    _Pragma("unroll") for (int kk = 0; kk < 2; ++kk) { \
      int ch = kk * 4 + lk; \
      int r0 = mh * 32 + lr, r1 = mh * 32 + 16 + lr; \
      s8v a0 = *(const s8v*)(base + r0 * 128 + ((ch ^ (r0 & 7)) << 4)); \
      s8v a1 = *(const s8v*)(base + r1 * 128 + ((ch ^ (r1 & 7)) << 4)); \
      int boff = 8192 + ch * 1024 + ((cq * 16 + lr) << 4); \
      s8v br = *(const s8v*)(base + boff); \
      s8v bu = *(const s8v*)(base + boff + 8192); \
      s8v bx = *(const s8v*)(base + boff + 16384); \
      accr0 = MFMA16(a0, br, accr0, 0, 0, 0); \
      accr1 = MFMA16(a1, br, accr1, 0, 0, 0); \
      accu0 = MFMA16(a0, bu, accu0, 0, 0, 0); \
      accu1 = MFMA16(a1, bu, accu1, 0, 0, 0); \
      X0 = MFMA16(a0, bx, X0, 0, 0, 0); \
      X1 = MFMA16(a1, bx, X1, 0, 0, 0); \
    } }

  G_STAGE(0)
  G_STAGE(1)
  for (int s = 0; s < 48; ++s) {
    if (s + 2 < 48) { G_STAGE(s + 2) }
    if (s < 46) asm volatile("s_waitcnt vmcnt(8)" ::: "memory");
    else if (s == 46) asm volatile("s_waitcnt vmcnt(4)" ::: "memory");
    else asm volatile("s_waitcnt vmcnt(0)" ::: "memory");
    RAW_BAR();
    if (s < 16) { G_COMP(s, acci0, acci1) }
    else { G_COMP(s, acch0, acch1) }
    RAW_BAR();
  }
#undef G_STAGE
#undef G_COMP

  // epilogue: gate math. C/D: col=lane&15, row=(lane>>4)*4+reg
  const int col = nt * 64 + cq * 16 + lr;
  const float b_r = bih[col] + bhh[col];
  const float b_u = bih[2048 + col] + bhh[2048 + col];
  const float b_ci = bih[4096 + col];
  const float b_ch = bhh[4096 + col];
#define G_EPI(AR, AU, AI, AH, MO) \
  _Pragma("unroll") for (int r = 0; r < 4; ++r) { \
    int grow = m0 + mh * 32 + (MO) + lk * 4 + r; \
    float vr = AR[r] + b_r; \
    float vu = AU[r] + b_u; \
    float ic = AI[r] + b_ci; \
    float hc = AH[r] + b_ch; \
    float rg = 1.f / (1.f + expf(-vr)); \
    float ug = 1.f / (1.f + expf(-vu)); \
    float c = tanhf(ic + rg * hc); \
    float hold = hf_r[(size_t)grow * 2048 + col]; \
    float h1 = (1.f - ug) * c + ug * hold; \
    hf_w[(size_t)grow * 2048 + col] = h1; \
    hcat_w[(size_t)grow * 2048 + col] = f2bf(h1); \
    feat[(size_t)(t * 256 + grow) * 2112 + col] = h1; \
  }
  G_EPI(accr0, accu0, acci0, acch0, 0)
  G_EPI(accr1, accu1, acci1, acch1, 16)
#undef G_EPI
}

// ---------------- posterior hidden GEMM: x = h1@posthW^T + b + e_part ------
// grid 128 (XCD swizzled), 256 thr, BM=32, BN=64, 32 stages, counted vmcnt.
__global__ __launch_bounds__(256) void k_post(
    const u16* __restrict__ hcat, const u16* __restrict__ wp,
    const float* __restrict__ bias, const u16* __restrict__ epart_t,
    float* __restrict__ xbuf) {
  const int hw = blockIdx.x;
  const int logical = (hw & 7) * 16 + (hw >> 3);
  const int mg = logical & 7, nt = logical >> 3;
  const int m0 = mg * 32;
  const int tid = threadIdx.x;
  const int lane = tid & 63;
  const int w = tid >> 6;
  const int lr = lane & 15, lk = lane >> 4;

  __shared__ __align__(16) char smem[2][12288];  // A 4KB + B 8KB

  const int arow = 8 * w + (lane >> 3);
  const int acol8 = ((lane & 7) ^ (arow & 7)) * 8;
  const u16* aSrc = hcat + (size_t)(m0 + arow) * 2048 + acol8;
  const u16* wpNt = wp + (size_t)nt * 32 * 4096;

  f4v acc[2];
  acc[0] = (f4v)(0.f);
  acc[1] = (f4v)(0.f);

#define K2_STAGE(BB, S) { \
    char* base = &smem[BB][0]; \
    glds16(aSrc + (S) * 64, base + w * 1024); \
    const u16* bsrc = wpNt + (size_t)(S) * 4096; \
    _Pragma("unroll") for (int i = 0; i < 2; ++i) { \
      int cf = w + i * 4; \
      glds16(bsrc + (cf * 64 + lane) * 8, base + 4096 + cf * 1024); \
    } }

#define K2_COMP(BB) { \
    char* base = &smem[BB][0]; \
    _Pragma("unroll") for (int kk = 0; kk < 2; ++kk) { \
      int ch = kk * 4 + lk; \
      int r0 = lr, r1 = 16 + lr; \
      s8v a0 = *(const s8v*)(base + r0 * 128 + ((ch ^ (r0 & 7)) * 16)); \
      s8v a1 = *(const s8v*)(base + r1 * 128 + ((ch ^ (r1 & 7)) * 16)); \
      s8v b = *(const s8v*)(base + 4096 + ch * 1024 + (w * 16 + lr) * 16); \
      acc[0] = MFMA16(a0, b, acc[0], 0, 0, 0); \
      acc[1] = MFMA16(a1, b, acc[1], 0, 0, 0); \
    } }

  K2_STAGE(0, 0)
  for (int s = 0; s < 31; ++s) {
    K2_STAGE((s + 1) & 1, s + 1)
    asm volatile("s_waitcnt vmcnt(3)" ::: "memory");
    RAW_BAR();
    K2_COMP(s & 1)
    RAW_BAR();
  }
  {
    asm volatile("s_waitcnt vmcnt(0)" ::: "memory");
    RAW_BAR();
    K2_COMP(1)
  }
#undef K2_STAGE
#undef K2_COMP
  const int col = nt * 64 + w * 16 + lr;
#pragma unroll
  for (int m = 0; m < 2; ++m) {
#pragma unroll
    for (int r = 0; r < 4; ++r) {
      int grow = m0 + m * 16 + lk * 4 + r;
      float v = acc[m][r] + bias[col] + bf2f(epart_t[(size_t)grow * 1024 + col]);
      xbuf[(size_t)grow * 1024 + col] = v;
    }
  }
}

// ------- posterior head: LN+ELU + GEMM + z-sample + za for next step -------
// grid 8, 512 thr. BM=32. Also computes za_{t+1} = elu(LN([z@zw^T+zb | a@aw^T]))
__global__ __launch_bounds__(512) void k_postz(
    const float* __restrict__ xb, const u16* __restrict__ pw,
    const float* __restrict__ lns, const float* __restrict__ lnb,
    const float* __restrict__ pb, float* __restrict__ posts_t,
    const float* __restrict__ noise_t, float* __restrict__ zout,
    float* __restrict__ feat, const u16* __restrict__ zwP,
    const float* __restrict__ zbv, const float* __restrict__ awT,
    const float* __restrict__ act_t, const float* __restrict__ lnzs,
    const float* __restrict__ lnzb, u16* __restrict__ za_out, int t) {
  const int m0 = blockIdx.x * 32;
  const int tid = threadIdx.x;
  const int lane = tid & 63;
  const int w = tid >> 6;  // 0..7
  const int lr = lane & 15, lk = lane >> 4;
  __shared__ __align__(16) u16 As[2][2048];   // 4KB x2
  __shared__ __align__(16) u16 Bs[2][8192];   // 16KB x2
  __shared__ float ps[32][132];
  __shared__ float lmu[32], lrsd[32];
  __shared__ __align__(16) u16 zbl[2048];     // z bf16, swizzled A-tile
  __shared__ float ash[320];                  // actions rows
  __shared__ __align__(16) char zal[65536];   // za pre-LN, chunk-swizzled
  __shared__ float zmu[32], zrsd[32];
  __shared__ float psum[16][32], qsum[16][32];

  if (tid < 320) ash[tid] = act_t[m0 * 10 + tid];
  {
    int row = tid >> 4, sg = tid & 15;
    const float4* xp = (const float4*)(xb + (size_t)(m0 + row) * 1024 + sg * 64);
    float s = 0.f, q = 0.f;
#pragma unroll
    for (int i = 0; i < 16; ++i) {
      float4 v = xp[i];
      s += v.x + v.y + v.z + v.w;
      q += v.x * v.x + v.y * v.y + v.z * v.z + v.w * v.w;
    }
#pragma unroll
    for (int o = 1; o < 16; o <<= 1) {
      s += __shfl_xor(s, o);
      q += __shfl_xor(q, o);
    }
    if (sg == 0) {
      float mu = s * (1.f / 1024.f);
      lmu[row] = mu;
      lrsd[row] = rsqrtf(q * (1.f / 1024.f) - mu * mu + LN_EPS);
    }
  }
  __syncthreads();

#define K3_STAGEA(BB, S) if (tid < 256) { \
    int row = tid >> 3, k8 = tid & 7; \
    const float* xp = xb + (size_t)(m0 + row) * 1024 + (S) * 64 + k8 * 8; \
    float mu = lmu[row], rs = lrsd[row]; \
    s8v v; \
    _Pragma("unroll") for (int e = 0; e < 8; ++e) { \
      int c = (S) * 64 + k8 * 8 + e; \
      float y = (xp[e] - mu) * rs * lns[c] + lnb[c]; \
      y = y > 0.f ? y : expm1f(y); \
      v[e] = (short)f2bf(y); \
    } \
    *(s8v*)((char*)&As[BB][0] + row * 128 + ((k8 ^ (row & 7)) * 16)) = v; }

#define K3_STAGEB(BB, S) { \
    const u16* bsrc = pw + (size_t)(S) * 8192; \
    glds16(bsrc + (w * 2) * 512 + lane * 8, (char*)&Bs[BB][0] + w * 2048); \
    glds16(bsrc + (w * 2 + 1) * 512 + lane * 8, (char*)&Bs[BB][0] + w * 2048 + 1024); }

  f4v acc0 = (f4v)(0.f), acc1 = (f4v)(0.f);
  K3_STAGEA(0, 0)
  K3_STAGEB(0, 0)
  int buf = 0;
  for (int s = 0; s < 16; ++s) {
    if (s + 1 < 16) {
      K3_STAGEA(buf ^ 1, s + 1)
      K3_STAGEB(buf ^ 1, s + 1)
      asm volatile("s_waitcnt vmcnt(2) lgkmcnt(0)" ::: "memory");
    } else {
      asm volatile("s_waitcnt vmcnt(0) lgkmcnt(0)" ::: "memory");
    }
    RAW_BAR();
#pragma unroll
    for (int kk = 0; kk < 2; ++kk) {
      int ch = kk * 4 + lk;
      int r0 = lr, r1 = 16 + lr;
      s8v a0 = *(const s8v*)((char*)&As[buf][0] + r0 * 128 + ((ch ^ (r0 & 7)) * 16));
      s8v a1 = *(const s8v*)((char*)&As[buf][0] + r1 * 128 + ((ch ^ (r1 & 7)) * 16));
      s8v b = *(const s8v*)((char*)&Bs[buf][0] + ch * 2048 + (w * 16 + lr) * 16);
      acc0 = MFMA16(a0, b, acc0, 0, 0, 0);
      acc1 = MFMA16(a1, b, acc1, 0, 0, 0);
    }
    __builtin_amdgcn_s_barrier();
    buf ^= 1;
  }
#undef K3_STAGEA
#undef K3_STAGEB

  {
    int colp = w * 16 + lr;
#pragma unroll
    for (int r = 0; r < 4; ++r) {
      int row0 = lk * 4 + r;
      float v0 = acc0[r] + pb[colp];
      posts_t[(size_t)(m0 + row0) * 128 + colp] = v0;
      ps[row0][colp] = v0;
      float v1 = acc1[r] + pb[colp];
      posts_t[(size_t)(m0 + 16 + row0) * 128 + colp] = v1;
      ps[16 + row0][colp] = v1;
    }
  }
  __syncthreads();
  // sample: z = mean + (2*sigmoid(sraw)+0.1)*noise; also stash z bf16 in zbl
#pragma unroll
  for (int q = 0; q < 4; ++q) {
    int e = q * 512 + tid;
    int row = e >> 6, j = e & 63;
    float mean = ps[row][j], sraw = ps[row][64 + j];
    float sd = 2.f / (1.f + expf(-sraw)) + 0.1f;
    float z = mean + sd * noise_t[(m0 + row) * 64 + j];
    zout[(m0 + row) * 64 + j] = z;
    feat[(size_t)(t * 256 + m0 + row) * 2112 + 2048 + j] = z;
    *(u16*)((char*)&zbl[0] + row * 128 + (((j >> 3) ^ (row & 7)) << 4) +
            (j & 7) * 2) = f2bf(z);
  }
  __syncthreads();

  // za a-part (cols 512..1023): VALU with coalesced awT
  {
    float acc[32];
#pragma unroll
    for (int r = 0; r < 32; ++r) acc[r] = 0.f;
#pragma unroll
    for (int k = 0; k < 10; ++k) {
      float wv = awT[k * 512 + tid];
#pragma unroll
      for (int r = 0; r < 32; ++r) acc[r] += ash[r * 10 + k] * wv;
    }
    int c = 512 + tid;
    int chs = c >> 3, cb = (c & 7) * 2;
#pragma unroll
    for (int r = 0; r < 32; ++r)
      *(u16*)(zal + r * 2048 + ((chs ^ (r & 7)) << 4) + cb) = f2bf(acc[r]);
  }
  // za z-part (cols 0..511): MFMA over 4 col-chunks of 128, B staged in Bs[0]
  for (int c4 = 0; c4 < 4; ++c4) {
    glds16(zwP + c4 * 8192 + (w * 2) * 512 + lane * 8, (char*)&Bs[0][0] + w * 2048);
    glds16(zwP + c4 * 8192 + (w * 2 + 1) * 512 + lane * 8,
           (char*)&Bs[0][0] + w * 2048 + 1024);
    asm volatile("s_waitcnt vmcnt(0)" ::: "memory");
    RAW_BAR();
    f4v z0 = (f4v)(0.f), z1 = (f4v)(0.f);
#pragma unroll
    for (int kk = 0; kk < 2; ++kk) {
      int ch = kk * 4 + lk;
      int r0 = lr, r1 = 16 + lr;
      s8v a0 = *(const s8v*)((char*)&zbl[0] + r0 * 128 + ((ch ^ (r0 & 7)) << 4));
      s8v a1 = *(const s8v*)((char*)&zbl[0] + r1 * 128 + ((ch ^ (r1 & 7)) << 4));
      s8v b = *(const s8v*)((char*)&Bs[0][0] + ch * 2048 + (w * 16 + lr) * 16);
      z0 = MFMA16(a0, b, z0, 0, 0, 0);
      z1 = MFMA16(a1, b, z1, 0, 0, 0);
    }
    int zcol = c4 * 128 + w * 16 + lr;
    int chz = zcol >> 3, cbz = (zcol & 7) * 2;
    float zbias = zbv[zcol];
#pragma unroll
    for (int r = 0; r < 4; ++r) {
      int ra = lk * 4 + r, rb = 16 + lk * 4 + r;
      *(u16*)(zal + ra * 2048 + ((chz ^ (ra & 7)) << 4) + cbz) = f2bf(z0[r] + zbias);
      *(u16*)(zal + rb * 2048 + ((chz ^ (rb & 7)) << 4) + cbz) = f2bf(z1[r] + zbias);
    }
    RAW_BAR();
  }
  __syncthreads();
  // za LN stats: each thread owns (g=tid>>5, row=tid&31) -> 64 cols; store
  // per-group partials in LDS, then 32 threads reduce the 16 groups.
  {
    int row = tid & 31, g = tid >> 5;
    float s = 0.f, q = 0.f;
#pragma unroll
    for (int jj = 0; jj < 8; ++jj) {
      int chunk = g * 8 + jj;
      s8v v = *(const s8v*)(zal + row * 2048 + ((chunk ^ (row & 7)) << 4));
#pragma unroll
      for (int e = 0; e < 8; ++e) {
        float x = bf2f((u16)v[e]);
        s += x;
        q += x * x;
      }
    }
    psum[g][row] = s;
    qsum[g][row] = q;
    __syncthreads();
    if (tid < 32) {
      float ss = 0.f, qq = 0.f;
#pragma unroll
      for (int gg = 0; gg < 16; ++gg) {
        ss += psum[gg][tid];
        qq += qsum[gg][tid];
      }
      float mu = ss * (1.f / 1024.f);
      zmu[tid] = mu;
      zrsd[tid] = rsqrtf(qq * (1.f / 1024.f) - mu * mu + LN_EPS);
    }
  }
  __syncthreads();
  // apply LN+ELU, write za_out
  {
    int row = tid >> 4, g = tid & 15;
    float mu = zmu[row], rs = zrsd[row];
    u16* dst = za_out + (size_t)(m0 + row) * 1024 + g * 64;
#pragma unroll
    for (int jj = 0; jj < 8; ++jj) {
      int chunk = g * 8 + jj;
      s8v v = *(const s8v*)(zal + row * 2048 + ((chunk ^ (row & 7)) << 4));
      s8v o;
#pragma unroll
      for (int e = 0; e < 8; ++e) {
        int c = chunk * 8 + e;
        float y = (bf2f((u16)v[e]) - mu) * rs * lnzs[c] + lnzb[c];
        y = y > 0.f ? y : expm1f(y);
        o[e] = (short)f2bf(y);
      }
      *(s8v*)(dst + jj * 8) = o;
    }
  }
}

// ---------------- batched 8-wave GEMM (embed / prior phases) ----------------
template <bool AF32, bool OUTBF16>
__global__ __launch_bounds__(512) void k_gemm8(
    const void* __restrict__ Av, int lda, const u16* __restrict__ Bw, int ldb,
    int nstage, float* __restrict__ Cf, u16* __restrict__ Cb, int ldc,
    const float* __restrict__ bias) {
  const int bx = blockIdx.x, by = blockIdx.y;
  const int tid = threadIdx.x;
  const int m0 = bx * 64;
  const int n0 = by * 128;
  __shared__ __align__(16) u16 As[64][72];
  __shared__ __align__(16) u16 Bs[128][72];
  const int lane = tid & 63;
  const int w = tid >> 6;
  const int wr = w >> 2;
  const int wc = w & 3;
  const int lr = lane & 15;
  const int lk = lane >> 4;

  f4v acc[2][2];
#pragma unroll
  for (int m = 0; m < 2; ++m)
#pragma unroll
    for (int n = 0; n < 2; ++n) acc[m][n] = (f4v)(0.0f);

  for (int s = 0; s < nstage; ++s) {
    const int k0 = s << 6;
    {
      int row = tid >> 3, k8 = (tid & 7) << 3;
      if (AF32) {
        const float* ap = (const float*)Av + (size_t)(m0 + row) * lda + k0 + k8;
        float4 f0 = *(const float4*)ap;
        float4 f1 = *(const float4*)(ap + 4);
        s8v v;
        v[0] = (short)f2bf(f0.x); v[1] = (short)f2bf(f0.y);
        v[2] = (short)f2bf(f0.z); v[3] = (short)f2bf(f0.w);
        v[4] = (short)f2bf(f1.x); v[5] = (short)f2bf(f1.y);
        v[6] = (short)f2bf(f1.z); v[7] = (short)f2bf(f1.w);
        *(s8v*)&As[row][k8] = v;
      } else {
        *(s8v*)&As[row][k8] =
            *(const s8v*)((const u16*)Av + (size_t)(m0 + row) * lda + k0 + k8);
      }
    }
#pragma unroll
    for (int it = 0; it < 2; ++it) {
      int c = tid + it * 512;
      int row = c >> 3, k8 = (c & 7) << 3;
      *(s8v*)&Bs[row][k8] = *(const s8v*)(Bw + (size_t)(n0 + row) * ldb + k0 + k8);
    }
    __syncthreads();
#pragma unroll
    for (int kk = 0; kk < 2; ++kk) {
      const int koff = kk * 32 + lk * 8;
      s8v a[2], b[2];
      a[0] = *(const s8v*)&As[wr * 32 + lr][koff];
      a[1] = *(const s8v*)&As[wr * 32 + 16 + lr][koff];
      b[0] = *(const s8v*)&Bs[wc * 32 + lr][koff];
      b[1] = *(const s8v*)&Bs[wc * 32 + 16 + lr][koff];
#pragma unroll
      for (int m = 0; m < 2; ++m)
#pragma unroll
        for (int n = 0; n < 2; ++n)
          acc[m][n] = MFMA16(a[m], b[n], acc[m][n], 0, 0, 0);
    }
    __syncthreads();
  }
#pragma unroll
  for (int m = 0; m < 2; ++m) {
#pragma unroll
    for (int n = 0; n < 2; ++n) {
#pragma unroll
      for (int r = 0; r < 4; ++r) {
        int row = m0 + wr * 32 + m * 16 + lk * 4 + r;
        int col = n0 + wc * 32 + n * 16 + lr;
        float v = acc[m][n][r];
        if (bias) v += bias[col];
        if (OUTBF16)
          Cb[(size_t)row * ldc + col] = f2bf(v);
        else
          Cf[(size_t)row * ldc + col] = v;
      }
    }
  }
}

// ---------------- LN + ELU (rows of 1024), bf16 in/out ----------------
__global__ __launch_bounds__(256) void k_lnelu(const u16* __restrict__ xsrc,
                                               const float* __restrict__ s,
                                               const float* __restrict__ bb,
                                               u16* __restrict__ out) {
  int row = blockIdx.x, tid = threadIdx.x;
  __shared__ float red[256];
  float v[4];
#pragma unroll
  for (int i = 0; i < 4; ++i) {
    size_t idx = (size_t)row * 1024 + tid + i * 256;
    v[i] = bf2f(xsrc[idx]);
  }
  float sm = v[0] + v[1] + v[2] + v[3];
  red[tid] = sm;
  __syncthreads();
  for (int o = 128; o > 0; o >>= 1) {
    if (tid < o) red[tid] += red[tid + o];
    __syncthreads();
  }
  float mu = red[0] * (1.0f / 1024.0f);
  __syncthreads();
  float q = 0.f;
#pragma unroll
  for (int i = 0; i < 4; ++i) {
    float d = v[i] - mu;
    q += d * d;
  }
  red[tid] = q;
  __syncthreads();
  for (int o = 128; o > 0; o >>= 1) {
    if (tid < o) red[tid] += red[tid + o];
    __syncthreads();
  }
  float rs = rsqrtf(red[0] * (1.0f / 1024.0f) + LN_EPS);
#pragma unroll
  for (int i = 0; i < 4; ++i) {
    int c = tid + i * 256;
    float y = (v[i] - mu) * rs * s[c] + bb[c];
    y = y > 0.f ? y : expm1f(y);
    out[(size_t)row * 1024 + c] = f2bf(y);
  }
}

extern "C" void kernel_launch(void* const* d_in, const int* in_sizes, int n_in,
                              void* d_out, int out_size, void* d_ws,
                              size_t ws_size, hipStream_t stream) {
  const float* embeds = (const float*)d_in[0];
  const float* actions = (const float*)d_in[1];
  const float* h_t = (const float*)d_in[2];
  const float* z_t = (const float*)d_in[3];
  const float* noise = (const float*)d_in[4];
  const float* z_mlp_w = (const float*)d_in[5];
  const float* z_mlp_b = (const float*)d_in[6];
  const float* a_mlp_w = (const float*)d_in[7];
  const float* ln_za_s = (const float*)d_in[8];
  const float* ln_za_b = (const float*)d_in[9];
  const float* gru_wih = (const float*)d_in[10];
  const float* gru_whh = (const float*)d_in[11];
  const float* gru_bih = (const float*)d_in[12];
  const float* gru_bhh = (const float*)d_in[13];
  const float* post_h_w = (const float*)d_in[14];
  const float* post_h_b = (const float*)d_in[15];
  const float* post_e_w = (const float*)d_in[16];
  const float* post_e_b = (const float*)d_in[17];
  const float* ln_post_s = (const float*)d_in[18];
  const float* ln_post_b = (const float*)d_in[19];
  const float* post_w = (const float*)d_in[20];
  const float* post_b = (const float*)d_in[21];
  const float* prior_h_w = (const float*)d_in[22];
  const float* prior_h_b = (const float*)d_in[23];
  const float* ln_prior_s = (const float*)d_in[24];
  const float* ln_prior_b = (const float*)d_in[25];
  const float* prior_w = (const float*)d_in[26];
  const float* prior_b = (const float*)d_in[27];

  float* out = (float*)d_out;
  float* out_priors = out;           // [64,256,128]
  float* out_posts = out + 2097152;  // [64,256,128]
  float* out_z = out + 4194304;      // [64,256,64]
  float* out_feat = out + 5242880;   // [64,256,2112]

  char* ws = (char*)d_ws;
  size_t off = 0;
  auto alloc = [&](size_t bytes) {
    char* p = ws + off;
    off += (bytes + 255) & ~(size_t)255;
    return p;
  };
  // region W: GRU wt pack during scan; prx_b during prior phase
  char* regW = alloc((size_t)32 * 48 * 12288 * 2);  // 37.75 MB
  u16* wt = (u16*)regW;
  u16* prx_b = (u16*)regW;
  u16* posthP = (u16*)alloc((size_t)1024 * 2048 * 2);
  u16* postwP = (u16*)alloc((size_t)128 * 1024 * 2);
  u16* poste_b = (u16*)alloc((size_t)1024 * 1536 * 2);
  u16* priorh_b = (u16*)alloc((size_t)1024 * 2048 * 2);
  u16* priorw_b = (u16*)alloc((size_t)128 * 1024 * 2);
  u16* zwP = (u16*)alloc((size_t)512 * 64 * 2);
  float* awT = (float*)alloc((size_t)10 * 512 * 4);
  u16* hcat0 = (u16*)alloc((size_t)256 * 2048 * 2);
  u16* hcat1 = (u16*)alloc((size_t)256 * 2048 * 2);
  float* hf0 = (float*)alloc((size_t)256 * 2048 * 4);
  float* hf1 = (float*)alloc((size_t)256 * 2048 * 4);
  float* xbuf = (float*)alloc((size_t)256 * 1024 * 4);
  u16* za = (u16*)alloc((size_t)256 * 1024 * 2);
  // region U: e_part during scan; p_pr during prior phase
  char* regU = alloc((size_t)16384 * 1024 * 2);  // 33.55 MB
  u16* e_part = (u16*)regU;
  u16* p_pr = (u16*)regU;

  u16* hcat[2] = {hcat0, hcat1};
  float* hf[2] = {hf0, hf1};

  // ---- packing + conversions + h init + za(t=0) ----
  k_packgru<<<9216, 256, 0, stream>>>(gru_wih, gru_whh, wt);
  k_packB<<<1024, 256, 0, stream>>>(post_h_w, posthP, 2048, 64, 262144);
  k_packB<<<64, 256, 0, stream>>>(post_w, postwP, 1024, 128, 16384);
  k_packB<<<16, 256, 0, stream>>>(z_mlp_w, zwP, 64, 128, 4096);
  k_trA<<<20, 256, 0, stream>>>(a_mlp_w, awT);
  k_cvt<<<512, 256, 0, stream>>>(post_e_w, poste_b, 1024 * 1536);
  k_cvt<<<512, 256, 0, stream>>>(prior_h_w, priorh_b, 1024 * 2048);
  k_cvt<<<64, 256, 0, stream>>>(prior_w, priorw_b, 128 * 1024);
  k_hinit<<<2048, 256, 0, stream>>>(h_t, hf0, hcat0);
  k_za0<<<256, 256, 0, stream>>>(z_t, actions, z_mlp_w, z_mlp_b, a_mlp_w,
                                 ln_za_s, ln_za_b, za);

  // ---- batched embed projection: e_part = embeds@post_e_w^T + post_e_b ----
  k_gemm8<true, true><<<dim3(256, 8), 512, 0, stream>>>(
      embeds, 1536, poste_b, 1536, 24, nullptr, e_part, 1024, post_e_b);

  // ---- sequential scan (3 launches/step) ----
  for (int t = 0; t < 64; ++t) {
    const int rI = t & 1, wI = rI ^ 1;
    k_gru<<<128, 512, 0, stream>>>(za, hcat[rI], wt, gru_bih, gru_bhh, hf[rI],
                                   hf[wI], hcat[wI], out_feat, t);
    k_post<<<128, 256, 0, stream>>>(hcat[wI], posthP, post_h_b,
                                    e_part + (size_t)t * 262144, xbuf);
    k_postz<<<8, 512, 0, stream>>>(
        xbuf, postwP, ln_post_s, ln_post_b, post_b,
        out_posts + (size_t)t * 32768, noise + (size_t)t * 16384,
        out_z + (size_t)t * 16384, out_feat, zwP, z_mlp_b, awT,
        actions + (size_t)(t + 1 < 64 ? t + 1 : t) * 2560, ln_za_s, ln_za_b,
        za, t);
  }

  // ---- batched prior head (wt/e_part dead; reuse regions) ----
  k_gemm8<true, true><<<dim3(256, 8), 512, 0, stream>>>(
      out_feat, 2112, priorh_b, 2048, 32, nullptr, prx_b, 1024, prior_h_b);
  k_lnelu<<<16384, 256, 0, stream>>>(prx_b, ln_prior_s, ln_prior_b, p_pr);
  k_gemm8<false, false><<<dim3(256, 1), 512, 0, stream>>>(
      p_pr, 1024, priorw_b, 1024, 16, out_priors, nullptr, 128, prior_b);
}